// Round 1
// baseline (225.457 us; speedup 1.0000x reference)
//
#include <hip/hip_runtime.h>

#define GRID_NUM_I 7
constexpr float IMG_SIZE = 448.0f;
constexpr float GSZ = 64.0f;           // IMG_SIZE / GRID_NUM
constexpr float LAMBDA_COORD = 5.0f;
constexpr float LAMBDA_NOOBJ = 0.1f;
constexpr float EPSF = 1e-12f;

// Faithful port of reference _iou (including the y1_t = cy_t + w_t/2 typo).
__device__ __forceinline__ float iou_one(const float* __restrict__ b,
                                         float tx, float ty, float tw, float th,
                                         float gj, float gi) {
    float cx_p = b[0] * GSZ + gj * GSZ;
    float cy_p = b[1] * GSZ + gi * GSZ;
    float w_p  = b[2] * IMG_SIZE;
    float h_p  = b[3] * IMG_SIZE;
    float x0p = cx_p - 0.5f * w_p, x1p = cx_p + 0.5f * w_p;
    float y0p = cy_p - 0.5f * h_p, y1p = cy_p + 0.5f * h_p;

    float cx_t = tx * GSZ + gj * GSZ;
    float cy_t = ty * GSZ + gi * GSZ;
    float w_t  = tw * IMG_SIZE;
    float h_t  = th * IMG_SIZE;
    float x0t = cx_t - 0.5f * w_t, x1t = cx_t + 0.5f * w_t;
    float y0t = cy_t - 0.5f * h_t;
    float y1t = cy_t + 0.5f * w_t;   // faithful typo: w_t, not h_t

    float ux0 = fmaxf(x0p, x0t), ux1 = fminf(x1p, x1t);
    float uy0 = fmaxf(y0p, y0t), uy1 = fminf(y1p, y1t);
    bool valid = (ux0 < ux1) && (uy0 < uy1);
    float au = (ux1 - ux0) * (uy1 - uy0);
    float ap = (x1p - x0p) * (y1p - y0p);
    float at = (x1t - x0t) * (y1t - y0t);
    float res = au / (ap + at - au + EPSF);
    return valid ? res : 0.0f;
}

// Per-cell loss contribution (already weighted; caller multiplies by 1/B later).
__device__ __forceinline__ float cell_loss(const float* __restrict__ p,
                                           const float* __restrict__ t,
                                           float gj, float gi) {
    float iou0 = iou_one(p,     t[0], t[1], t[2], t[3], gj, gi);
    float iou1 = iou_one(p + 5, t[0], t[1], t[2], t[3], gj, gi);
    bool obj = (t[4] == 1.0f);
    bool ch0 = iou0 > iou1;
    float loss;
    if (obj) {
        float cp = ch0 ? p[4] : p[9];
        float ct = ch0 ? iou0 : iou1;
        float d  = cp - ct;
        loss = d * d;
        float dx = (ch0 ? p[0] : p[5]) - t[0];
        float dy = (ch0 ? p[1] : p[6]) - t[1];
        loss += LAMBDA_COORD * (dx * dx + dy * dy);
        float wp = fmaxf(ch0 ? p[2] : p[7], EPSF);
        float hp = fmaxf(ch0 ? p[3] : p[8], EPSF);
        float wt = fmaxf(t[2], EPSF);
        float ht = fmaxf(t[3], EPSF);
        float dw = sqrtf(wp) - sqrtf(wt);
        float dh = sqrtf(hp) - sqrtf(ht);
        loss += LAMBDA_COORD * (dw * dw + dh * dh);
    } else {
        loss = LAMBDA_NOOBJ * (p[4] * p[4] + p[9] * p[9]);
    }
    return loss;
}

__global__ __launch_bounds__(256)
void yolo_loss_kernel(const float* __restrict__ y_pre,
                      const float* __restrict__ y_true,
                      float* __restrict__ out,
                      int ngroups, int cells, float invB) {
    int t = blockIdx.x * blockDim.x + threadIdx.x;
    float local = 0.0f;

    if (t < ngroups) {
        // 4 cells per thread -> perfectly aligned float4 traffic on both inputs.
        float p[40];
        float tr[20];
        const float4* pp = (const float4*)(y_pre) + (size_t)t * 10;
        #pragma unroll
        for (int i = 0; i < 10; ++i) {
            float4 v = pp[i];
            p[4 * i + 0] = v.x; p[4 * i + 1] = v.y;
            p[4 * i + 2] = v.z; p[4 * i + 3] = v.w;
        }
        const float4* tp = (const float4*)(y_true) + (size_t)t * 5;
        #pragma unroll
        for (int i = 0; i < 5; ++i) {
            float4 v = tp[i];
            tr[4 * i + 0] = v.x; tr[4 * i + 1] = v.y;
            tr[4 * i + 2] = v.z; tr[4 * i + 3] = v.w;
        }
        int c0 = t * 4;
        int rc = c0 % 49;            // cell index within the 7x7 image
        #pragma unroll
        for (int k = 0; k < 4; ++k) {
            int gi = rc / 7;
            int gj = rc % 7;
            local += cell_loss(p + 10 * k, tr + 5 * k, (float)gj, (float)gi);
            ++rc; if (rc == 49) rc = 0;
        }
    }

    // Scalar tail (cells % 4 != 0) — not hit for this shape, kept for safety.
    if (t == 0) {
        for (int c = ngroups * 4; c < cells; ++c) {
            const float* p = y_pre + (size_t)c * 10;
            const float* tr = y_true + (size_t)c * 5;
            int rc = c % 49;
            local += cell_loss(p, tr, (float)(rc % 7), (float)(rc / 7));
        }
    }

    // Wave-64 shuffle reduce.
    #pragma unroll
    for (int off = 32; off > 0; off >>= 1)
        local += __shfl_down(local, off, 64);

    __shared__ float smem[4];        // 256 threads = 4 waves
    int lane = threadIdx.x & 63;
    int wid  = threadIdx.x >> 6;
    if (lane == 0) smem[wid] = local;
    __syncthreads();
    if (threadIdx.x == 0) {
        float s = smem[0] + smem[1] + smem[2] + smem[3];
        atomicAdd(out, s * invB);
    }
}

extern "C" void kernel_launch(void* const* d_in, const int* in_sizes, int n_in,
                              void* d_out, int out_size, void* d_ws, size_t ws_size,
                              hipStream_t stream) {
    const float* y_pre  = (const float*)d_in[0];
    const float* y_true = (const float*)d_in[1];
    float* out = (float*)d_out;

    int cells   = in_sizes[0] / 10;          // B * 7 * 7
    int B       = cells / 49;
    int ngroups = cells / 4;
    float invB  = 1.0f / (float)B;

    hipMemsetAsync(out, 0, sizeof(float), stream);  // d_out is poisoned to 0xAA

    int blocks = (ngroups + 255) / 256;
    yolo_loss_kernel<<<blocks, 256, 0, stream>>>(y_pre, y_true, out, ngroups, cells, invB);
}